// Round 1
// baseline (72.652 us; speedup 1.0000x reference)
//
#include <hip/hip_runtime.h>

#define SIGMA 0.1f
#define RHO   10.0f
#define B     8
#define F     64

// One wave (64 lanes) per (b1,b2,i) row. Lane j owns column j.
__global__ __launch_bounds__(64) void row_kernel(
    const float* __restrict__ sim,
    const float* __restrict__ pos,
    const float* __restrict__ neg,
    float* __restrict__ r_out)  // [B*B*F] per-row value: pos_divide/pos_cnt
{
    const int row = blockIdx.x;          // 0 .. B*B*F-1
    const int j   = threadIdx.x;         // 0 .. 63

    __shared__ float ls[F];
    __shared__ float lp[F];
    __shared__ float ln[F];

    const size_t base = (size_t)row * F;
    ls[j] = sim[base + j];
    lp[j] = pos[base + j];
    ln[j] = neg[base + j];
    __syncthreads();

    const float sj  = ls[j];
    const bool  pj1 = lp[j] > 0.5f;     // pos[i,j] == 1

    float all_acc = 0.0f;
    float pos_acc = 0.0f;

    #pragma unroll 8
    for (int k = 0; k < F; ++k) {
        const float d   = ls[k] - sj;            // sim[i,k] - sim[i,j]
        const bool  pk  = lp[k] > 0.5f;
        const bool  nk  = ln[k] > 0.5f;
        const bool  pp  = pj1 && pk;             // pos_pos == 1
        const bool  pn  = pj1 && nk;             // pos_neg == 1

        float val;
        if (pp) {
            val = (d > 0.0f) ? RHO : 0.0f;       // rho * heaviside(d)
        } else if (pn) {
            const float xs = d * (1.0f / SIGMA);
            if (d > 0.0f)            val = 2.0f * xs + 1.0f;
            else if (d >= -SIGMA)    val = xs * xs + 2.0f * xs + 1.0f;
            else                     val = 0.0f;
        } else {
            val = 0.0f;
        }
        if (k == j) val = 0.0f;                  // off-diagonal mask

        all_acc += val;
        pos_acc += pp ? val : 0.0f;
    }

    const float all_rk = all_acc + 1.0f;
    const float pos_rk = pos_acc + 1.0f;

    float term = (pos_rk / all_rk) * (pj1 ? 1.0f : 0.0f);  // * pos[i,j]
    float cnt  = pj1 ? 1.0f : 0.0f;

    // wave-64 reduction
    #pragma unroll
    for (int off = 32; off > 0; off >>= 1) {
        term += __shfl_down(term, off, 64);
        cnt  += __shfl_down(cnt,  off, 64);
    }

    if (j == 0) r_out[row] = term / cnt;         // pos_divide_vec / pos_cnt_vec
}

// Single wave: ap[p] = mean_i r[p*F+i]; out = 1 - sum(ap*label)/sum(label)
__global__ __launch_bounds__(64) void finish_kernel(
    const float* __restrict__ r,
    const float* __restrict__ label,
    float* __restrict__ out)
{
    const int p = threadIdx.x;                   // 0 .. 63 == (b1,b2) pair

    float acc = 0.0f;
    #pragma unroll 8
    for (int i = 0; i < F; ++i) acc += r[p * F + i];
    const float ap  = acc * (1.0f / F);
    const float lab = label[p];

    float s1 = ap * lab;
    float s2 = lab;
    #pragma unroll
    for (int off = 32; off > 0; off >>= 1) {
        s1 += __shfl_down(s1, off, 64);
        s2 += __shfl_down(s2, off, 64);
    }

    if (p == 0) out[0] = 1.0f - s1 / s2;
}

extern "C" void kernel_launch(void* const* d_in, const int* in_sizes, int n_in,
                              void* d_out, int out_size, void* d_ws, size_t ws_size,
                              hipStream_t stream)
{
    const float* sim   = (const float*)d_in[0];  // [B,B,F,F]
    const float* pos   = (const float*)d_in[1];  // [B,B,F,F]
    const float* neg   = (const float*)d_in[2];  // [B,B,F,F]
    const float* label = (const float*)d_in[3];  // [B,B]
    float*       out   = (float*)d_out;          // scalar
    float*       r     = (float*)d_ws;           // [B*B*F] scratch

    row_kernel<<<B * B * F, 64, 0, stream>>>(sim, pos, neg, r);
    finish_kernel<<<1, 64, 0, stream>>>(r, label, out);
}

// Round 2
// 67.833 us; speedup vs baseline: 1.0710x; 1.0710x over previous
//
#include <hip/hip_runtime.h>

#define SIGMA 0.1f
#define RHO   10.0f
#define B     8
#define F     64
#define ROWS_PER_BLOCK 4

// 1024 blocks x 256 threads; wave w handles row = blockIdx*4 + w.
// All 4 rows of a block belong to the same (b1,b2) pair (4 | 64).
// Emits per-block partial of:  sum_rows (pos_divide/pos_cnt) * (1/F) * label[pair]
__global__ __launch_bounds__(256) void row_kernel(
    const float* __restrict__ sim,
    const float* __restrict__ pos,
    const float* __restrict__ neg,
    const float* __restrict__ label,
    float* __restrict__ partial)   // [1024]
{
    const int lane = threadIdx.x & 63;
    const int w    = threadIdx.x >> 6;
    const int row  = blockIdx.x * ROWS_PER_BLOCK + w;
    const int pair = row >> 6;               // row / F

    __shared__ float ls[ROWS_PER_BLOCK][F];
    __shared__ float psum[ROWS_PER_BLOCK];

    const size_t base = (size_t)row * F;
    const float sj = sim[base + lane];
    const float pj = pos[base + lane];
    const float nj = neg[base + lane];
    ls[w][lane] = sj;                        // wave-synchronous; no barrier needed

    // wave-uniform 64-bit predicate masks
    const unsigned long long pmask = __ballot(pj > 0.5f);
    const unsigned long long nonly = __ballot(nj > 0.5f) & ~pmask;

    float all_acc = 0.0f;
    float pos_acc = 0.0f;

    for (int k = 0; k < F; ++k) {
        if ((pmask >> k) & 1ull) {
            // pos_pos path: rho * heaviside(d); d==0 at k==lane self-zeroes
            const float d = ls[w][k] - sj;
            const float v = (d > 0.0f) ? RHO : 0.0f;
            all_acc += v;
            pos_acc += v;
        } else if ((nonly >> k) & 1ull) {
            // pos_neg path: quad_linear(d). k==lane here implies pj==0, whose
            // term is annihilated below, so no diagonal masking needed.
            const float d  = ls[w][k] - sj;
            const float xs = d * (1.0f / SIGMA);
            const float t  = xs + 1.0f;
            const float v  = (d > 0.0f) ? fmaf(2.0f, xs, 1.0f)
                                        : ((t >= 0.0f) ? t * t : 0.0f);
            all_acc += v;
        }
        // neither pos nor neg: contributes 0, skip
    }

    const float all_rk = all_acc + 1.0f;     // >= 1, no div hazard
    const float pos_rk = pos_acc + 1.0f;

    float term = (pj > 0.5f) ? (pos_rk / all_rk) : 0.0f;
    float cntv = (pj > 0.5f) ? 1.0f : 0.0f;

    #pragma unroll
    for (int off = 32; off > 0; off >>= 1) {
        term += __shfl_down(term, off, 64);
        cntv += __shfl_down(cntv, off, 64);
    }

    if (lane == 0) psum[w] = term / cntv;    // this row's pos_divide/pos_cnt
    __syncthreads();

    if (threadIdx.x == 0) {
        const float lab = label[pair];
        const float s = psum[0] + psum[1] + psum[2] + psum[3];
        partial[blockIdx.x] = s * (1.0f / F) * lab;
    }
}

// 1 block x 256 threads: num = sum(partial[0..1023]); den = sum(label[0..63]);
// out = 1 - num/den
__global__ __launch_bounds__(256) void finish_kernel(
    const float* __restrict__ partial,
    const float* __restrict__ label,
    float* __restrict__ out)
{
    const int t    = threadIdx.x;
    const int lane = t & 63;
    const int w    = t >> 6;

    const float4 v = ((const float4*)partial)[t];   // coalesced, 16 B/lane
    float s = v.x + v.y + v.z + v.w;
    #pragma unroll
    for (int off = 32; off > 0; off >>= 1) s += __shfl_down(s, off, 64);

    __shared__ float sm[4];
    if (lane == 0) sm[w] = s;
    __syncthreads();

    if (t < 64) {
        float den = label[t];
        #pragma unroll
        for (int off = 32; off > 0; off >>= 1) den += __shfl_down(den, off, 64);
        if (t == 0) {
            const float num = sm[0] + sm[1] + sm[2] + sm[3];
            out[0] = 1.0f - num / den;
        }
    }
}

extern "C" void kernel_launch(void* const* d_in, const int* in_sizes, int n_in,
                              void* d_out, int out_size, void* d_ws, size_t ws_size,
                              hipStream_t stream)
{
    const float* sim   = (const float*)d_in[0];  // [B,B,F,F]
    const float* pos   = (const float*)d_in[1];  // [B,B,F,F]
    const float* neg   = (const float*)d_in[2];  // [B,B,F,F]
    const float* label = (const float*)d_in[3];  // [B,B]
    float*       out   = (float*)d_out;          // scalar
    float*       part  = (float*)d_ws;           // [1024] partials

    row_kernel<<<(B * B * F) / ROWS_PER_BLOCK, 256, 0, stream>>>(sim, pos, neg, label, part);
    finish_kernel<<<1, 256, 0, stream>>>(part, label, out);
}